// Round 1
// baseline (5013.889 us; speedup 1.0000x reference)
//
#include <hip/hip_runtime.h>

#define VOCAB  96
#define EMBED  32
#define HIDDEN 128
#define BATCH  512
#define TLEN   2048
#define KW     (EMBED + HIDDEN)   // 160

// Kernel A: Pe[v][i] = b_cell[i] + sum_k emb[v,k] * We[i,k]   (96 x 128 table)
__global__ void pe_precompute(const float* __restrict__ emb,
                              const float* __restrict__ W_cell,
                              const float* __restrict__ b_cell,
                              float* __restrict__ Pe) {
    const int tid = blockIdx.x * blockDim.x + threadIdx.x;
    if (tid >= VOCAB * HIDDEN) return;
    const int v = tid >> 7;            // /HIDDEN
    const int i = tid & (HIDDEN - 1);
    float acc = b_cell[i];
    const float* e = emb + v * EMBED;
    const float* w = W_cell + i * KW;  // We row
    #pragma unroll
    for (int k = 0; k < EMBED; ++k) acc = fmaf(e[k], w[k], acc);
    Pe[tid] = acc;
}

// Kernel B: fused recurrence + decode. One block = one batch row.
// Thread i owns h-element i (Wh row in regs) and out-element i (<96, W_dec row in regs).
__global__ __launch_bounds__(HIDDEN, 1)
void rnn_fused(const int* __restrict__ x,
               const float* __restrict__ h0,
               const float* __restrict__ W_cell,
               const float* __restrict__ W_dec,
               const float* __restrict__ b_dec,
               const float* __restrict__ Pe,
               float* __restrict__ out) {
    __shared__ float pe_lds[VOCAB * HIDDEN];          // 48 KB
    __shared__ int   x_lds[TLEN];                      // 8 KB
    __shared__ __align__(16) float h_lds[2][HIDDEN];   // 1 KB double buffer

    const int i   = threadIdx.x;
    const int row = blockIdx.x;

    // Wh row -> registers (128 VGPRs)
    float wh[HIDDEN];
    {
        const float* src = W_cell + i * KW + EMBED;
        #pragma unroll
        for (int k = 0; k < HIDDEN / 4; ++k) {
            const float4 w = *(const float4*)(src + 4 * k);
            wh[4*k+0] = w.x; wh[4*k+1] = w.y; wh[4*k+2] = w.z; wh[4*k+3] = w.w;
        }
    }
    // W_dec row -> registers (128 VGPRs, threads < 96)
    float wd[HIDDEN];
    float bd = 0.f;
    if (i < VOCAB) {
        const float* src = W_dec + i * HIDDEN;
        #pragma unroll
        for (int k = 0; k < HIDDEN / 4; ++k) {
            const float4 w = *(const float4*)(src + 4 * k);
            wd[4*k+0] = w.x; wd[4*k+1] = w.y; wd[4*k+2] = w.z; wd[4*k+3] = w.w;
        }
        bd = b_dec[i];
    }

    // Stage Pe table, token row, initial h
    for (int n = i; n < VOCAB * HIDDEN; n += HIDDEN) pe_lds[n] = Pe[n];
    for (int n = i; n < TLEN; n += HIDDEN)           x_lds[n]  = x[row * TLEN + n];
    h_lds[0][i] = h0[row * HIDDEN + i];
    __syncthreads();

    float* outp = out + (size_t)row * TLEN * VOCAB + i;
    float hn = 0.f;

    for (int t = 0; t < TLEN; ++t) {
        const int cur = t & 1;
        const int tok = x_lds[t];                       // wave-uniform broadcast
        float acc = pe_lds[tok * HIDDEN + i];           // conflict-free

        // acc += Wh[i,:] . h   (h broadcast from LDS, weights in regs)
        const float4* hv4 = (const float4*)h_lds[cur];
        #pragma unroll
        for (int k = 0; k < HIDDEN / 4; ++k) {
            const float4 hv = hv4[k];
            acc = fmaf(wh[4*k+0], hv.x, acc);
            acc = fmaf(wh[4*k+1], hv.y, acc);
            acc = fmaf(wh[4*k+2], hv.z, acc);
            acc = fmaf(wh[4*k+3], hv.w, acc);
        }

        // fast tanh: 1 - 2/(exp(2x)+1), clamped (values are O(1); clamp is safety)
        const float xa = fminf(fmaxf(acc, -12.f), 12.f);
        const float e2 = __expf(2.f * xa);
        hn = 1.f - 2.f / (e2 + 1.f);

        h_lds[cur ^ 1][i] = hn;
        __syncthreads();   // single barrier per step (double buffer makes this safe)

        // decode: out[row,t,i] = W_dec[i,:] . h_next + b_dec[i]
        if (i < VOCAB) {
            float o = bd;
            const float4* nh4 = (const float4*)h_lds[cur ^ 1];
            #pragma unroll
            for (int k = 0; k < HIDDEN / 4; ++k) {
                const float4 hv = nh4[k];
                o = fmaf(wd[4*k+0], hv.x, o);
                o = fmaf(wd[4*k+1], hv.y, o);
                o = fmaf(wd[4*k+2], hv.z, o);
                o = fmaf(wd[4*k+3], hv.w, o);
            }
            outp[(size_t)t * VOCAB] = o;
        }
    }

    // h_final
    out[(size_t)BATCH * TLEN * VOCAB + row * HIDDEN + i] = hn;
}

extern "C" void kernel_launch(void* const* d_in, const int* in_sizes, int n_in,
                              void* d_out, int out_size, void* d_ws, size_t ws_size,
                              hipStream_t stream) {
    const int*   x      = (const int*)  d_in[0];
    const float* h0     = (const float*)d_in[1];
    const float* emb    = (const float*)d_in[2];
    const float* W_cell = (const float*)d_in[3];
    const float* b_cell = (const float*)d_in[4];
    const float* W_dec  = (const float*)d_in[5];
    const float* b_dec  = (const float*)d_in[6];
    float* out = (float*)d_out;
    float* Pe  = (float*)d_ws;   // 96*128*4 = 48 KB scratch

    pe_precompute<<<(VOCAB * HIDDEN + 127) / 128, 128, 0, stream>>>(emb, W_cell, b_cell, Pe);
    rnn_fused<<<BATCH, HIDDEN, 0, stream>>>(x, h0, W_cell, W_dec, b_dec, Pe, out);
}

// Round 2
// 2816.156 us; speedup vs baseline: 1.7804x; 1.7804x over previous
//
#include <hip/hip_runtime.h>
#include <hip/hip_bf16.h>

#define VOCAB  96
#define EMBED  32
#define HIDDEN 128
#define BATCH  512
#define TLEN   2048
#define KW     (EMBED + HIDDEN)   // 160
#define MROWS  (BATCH * TLEN)     // 1,048,576

typedef __attribute__((ext_vector_type(8))) short short8;    // 8 x bf16 bits
typedef __attribute__((ext_vector_type(4))) float float4v;

static __device__ __forceinline__ unsigned short f2bf_bits(float f) {
    __hip_bfloat16 b = __float2bfloat16(f);
    return *(unsigned short*)&b;
}

// ---------------------------------------------------------------------------
// Kernel A: Pe[v][i] = b_cell[i] + sum_k emb[v,k] * We[i,k]   (96 x 128)
// ---------------------------------------------------------------------------
__global__ void pe_precompute(const float* __restrict__ emb,
                              const float* __restrict__ W_cell,
                              const float* __restrict__ b_cell,
                              float* __restrict__ Pe) {
    const int tid = blockIdx.x * blockDim.x + threadIdx.x;
    if (tid >= VOCAB * HIDDEN) return;
    const int v = tid >> 7;
    const int i = tid & (HIDDEN - 1);
    float acc = b_cell[i];
    const float* e = emb + v * EMBED;
    const float* w = W_cell + i * KW;
    #pragma unroll
    for (int k = 0; k < EMBED; ++k) acc = fmaf(e[k], w[k], acc);
    Pe[tid] = acc;
}

// ---------------------------------------------------------------------------
// Kernel A2: W_dec fp32 -> bf16 bits (96 x 128)
// ---------------------------------------------------------------------------
__global__ void wdec_convert(const float* __restrict__ W_dec,
                             unsigned short* __restrict__ Wd) {
    const int tid = blockIdx.x * blockDim.x + threadIdx.x;
    if (tid < VOCAB * HIDDEN) Wd[tid] = f2bf_bits(W_dec[tid]);
}

// ---------------------------------------------------------------------------
// Kernel B: recurrence only. One block = one batch row, 128 threads.
// Thread i owns h-element i; Wh row i lives in 128 VGPRs (nothing else big).
// Stashes h_t (bf16) into the first 256 B of output row (b*T+t)'s 384 B slot.
// ---------------------------------------------------------------------------
__global__ __launch_bounds__(HIDDEN, 1)
void rnn_recur(const int* __restrict__ x,
               const float* __restrict__ h0,
               const float* __restrict__ W_cell,
               const float* __restrict__ Pe,
               float* __restrict__ out) {
    __shared__ float pe_lds[VOCAB * HIDDEN];           // 48 KB
    __shared__ int   x_lds[TLEN];                      // 8 KB
    __shared__ __align__(16) float h_lds[2][HIDDEN];

    const int i   = threadIdx.x;
    const int row = blockIdx.x;

    // Wh row -> registers (128 VGPRs). Only weight array in this kernel.
    float wh[HIDDEN];
    {
        const float* src = W_cell + i * KW + EMBED;
        #pragma unroll
        for (int k = 0; k < HIDDEN / 4; ++k) {
            const float4 w = *(const float4*)(src + 4 * k);
            wh[4*k+0] = w.x; wh[4*k+1] = w.y; wh[4*k+2] = w.z; wh[4*k+3] = w.w;
        }
    }

    for (int n = i; n < VOCAB * HIDDEN; n += HIDDEN) pe_lds[n] = Pe[n];
    for (int n = i; n < TLEN; n += HIDDEN)           x_lds[n]  = x[row * TLEN + n];
    h_lds[0][i] = h0[row * HIDDEN + i];
    __syncthreads();

    float hn = 0.f;
    const size_t rowbase = (size_t)row * TLEN;

    for (int t = 0; t < TLEN; ++t) {
        const int cur = t & 1;
        const int tok = x_lds[t];                       // wave-uniform broadcast

        // 4 independent accumulator chains (break the 128-FMA dep chain)
        float a0 = pe_lds[tok * HIDDEN + i];
        float a1 = 0.f, a2 = 0.f, a3 = 0.f;
        const float4* hv4 = (const float4*)h_lds[cur];
        #pragma unroll
        for (int k = 0; k < HIDDEN / 4; ++k) {
            const float4 hv = hv4[k];
            a0 = fmaf(wh[4*k+0], hv.x, a0);
            a1 = fmaf(wh[4*k+1], hv.y, a1);
            a2 = fmaf(wh[4*k+2], hv.z, a2);
            a3 = fmaf(wh[4*k+3], hv.w, a3);
        }
        const float acc = (a0 + a1) + (a2 + a3);

        // tanh = 1 - 2/(exp(2x)+1)
        const float xa = fminf(fmaxf(acc, -12.f), 12.f);
        const float e2 = __expf(2.f * xa);
        hn = 1.f - 2.f / (e2 + 1.f);

        h_lds[cur ^ 1][i] = hn;

        // stash bf16 h_t into this output row's own slot (off critical path)
        ((unsigned short*)(out + (rowbase + t) * VOCAB))[i] = f2bf_bits(hn);

        __syncthreads();   // single barrier per step (double buffer)
    }

    // h_final (fp32, tail of out)
    out[(size_t)MROWS * VOCAB + row * HIDDEN + i] = hn;
}

// ---------------------------------------------------------------------------
// Kernel C: decode GEMM via bf16 MFMA 16x16x32.
// Block = 256 threads = 4 waves; wave w handles 16 rows. Reads its rows'
// bf16 h-stash (front of each row's out slot), then overwrites the full rows.
// A-frag: A[m=lane&15][k=quad*8+j]; B-frag: B[k=quad*8+j][n=lane&15];
// D: col=lane&15, row=quad*4+reg.
// ---------------------------------------------------------------------------
__global__ __launch_bounds__(256)
void decode_mfma(const unsigned short* __restrict__ Wd,
                 const float* __restrict__ b_dec,
                 float* __restrict__ out) {
    const int wave = threadIdx.x >> 6;
    const int lane = threadIdx.x & 63;
    const int mrow = lane & 15;
    const int quad = lane >> 4;
    const int rowbase = (blockIdx.x * 4 + wave) * 16;

    // A fragments: 4 k-tiles of this lane's row
    const unsigned short* stash =
        (const unsigned short*)(out + (size_t)(rowbase + mrow) * VOCAB);
    short8 a[4];
    #pragma unroll
    for (int kt = 0; kt < 4; ++kt)
        a[kt] = *(const short8*)(stash + kt * 32 + quad * 8);

    #pragma unroll
    for (int nt = 0; nt < 6; ++nt) {
        const int ncol = nt * 16 + mrow;
        const unsigned short* wrow = Wd + ncol * HIDDEN + quad * 8;
        float4v acc = {0.f, 0.f, 0.f, 0.f};
        #pragma unroll
        for (int kt = 0; kt < 4; ++kt) {
            const short8 b = *(const short8*)(wrow + kt * 32);
            acc = __builtin_amdgcn_mfma_f32_16x16x32_bf16(a[kt], b, acc, 0, 0, 0);
        }
        const float bias = b_dec[ncol];
        #pragma unroll
        for (int r = 0; r < 4; ++r) {
            out[(size_t)(rowbase + quad * 4 + r) * VOCAB + ncol] = acc[r] + bias;
        }
    }
}

extern "C" void kernel_launch(void* const* d_in, const int* in_sizes, int n_in,
                              void* d_out, int out_size, void* d_ws, size_t ws_size,
                              hipStream_t stream) {
    const int*   x      = (const int*)  d_in[0];
    const float* h0     = (const float*)d_in[1];
    const float* emb    = (const float*)d_in[2];
    const float* W_cell = (const float*)d_in[3];
    const float* b_cell = (const float*)d_in[4];
    const float* W_dec  = (const float*)d_in[5];
    const float* b_dec  = (const float*)d_in[6];
    float* out = (float*)d_out;

    float*          Pe = (float*)d_ws;                          // 48 KB
    unsigned short* Wd = (unsigned short*)((char*)d_ws + VOCAB * HIDDEN * sizeof(float)); // 24 KB

    pe_precompute<<<(VOCAB * HIDDEN + 127) / 128, 128, 0, stream>>>(emb, W_cell, b_cell, Pe);
    wdec_convert<<<(VOCAB * HIDDEN + 255) / 256, 256, 0, stream>>>(W_dec, Wd);
    rnn_recur<<<BATCH, HIDDEN, 0, stream>>>(x, h0, W_cell, Pe, out);
    decode_mfma<<<MROWS / 64, 256, 0, stream>>>(Wd, b_dec, out);
}